// Round 10
// baseline (420.061 us; speedup 1.0000x reference)
//
#include <hip/hip_runtime.h>
#include <stdint.h>

#define D_MODEL 1024
#define T_SEQ   2048
#define N_BATCH 4
#define M_ROWS  (N_BATCH*T_SEQ)   // 8192
#define N_STATE 16
#define SEGS    32
#define SEGLEN  (T_SEQ/SEGS)      // 64
#define CHUNK   8
#define NCHUNK  (SEGLEN/CHUNK)    // 8

typedef float  f32x4  __attribute__((ext_vector_type(4)));
typedef __bf16 bf16x8 __attribute__((ext_vector_type(8)));
typedef __bf16 bf16x4 __attribute__((ext_vector_type(4)));

__device__ __forceinline__ void gload16(const void* g, void* l) {
  __builtin_amdgcn_global_load_lds(
      (const __attribute__((address_space(1))) uint32_t*)g,
      (__attribute__((address_space(3))) uint32_t*)l, 16, 0, 0);
}

__device__ __forceinline__ float sigmoidf_(float v){ return 1.f/(1.f+__expf(-v)); }

// ---------------- cast fp32 -> bf16 ----------------
__global__ __launch_bounds__(256) void cast_bf16_kernel(const float* __restrict__ in,
                                                        __bf16* __restrict__ out, int n4){
  int i = blockIdx.x*256 + threadIdx.x;
  if (i >= n4) return;
  float4 v = ((const float4*)in)[i];
  bf16x4 o; o[0]=(__bf16)v.x; o[1]=(__bf16)v.y; o[2]=(__bf16)v.z; o[3]=(__bf16)v.w;
  ((bf16x4*)out)[i] = o;
}

// ---------------- transpose + cast: W (K x N) fp32 -> out (N x K) bf16 ----------------
__global__ __launch_bounds__(256) void transpose_cast_kernel(const float* __restrict__ W,
                                                             __bf16* __restrict__ out,
                                                             int K, int N){
  __shared__ float tile[32][33];
  const int tx = threadIdx.x, ty = threadIdx.y;
  const int n0 = blockIdx.x*32, k0 = blockIdx.y*32;
  #pragma unroll
  for (int i=0;i<4;i++)
    tile[ty+i*8][tx] = W[(size_t)(k0+ty+i*8)*N + n0+tx];
  __syncthreads();
  #pragma unroll
  for (int i=0;i<4;i++)
    out[(size_t)(n0+ty+i*8)*K + k0+tx] = (__bf16)tile[tx][ty+i*8];
}

// ---- MFMA GEMM: C = A(MxK)*Bt(NxK)^T ----
// 2-phase dbuf, ONE __syncthreads per K-step (R8-proven), XCD swizzle.
// Tile size templated: BIG = 256x256 / 512 thr / 8 waves (2x4), wave-tile 128x64
//                      SMALL = 128x128 / 256 thr / 4 waves (2x2), wave-tile 64x64
#define BK 32

// EPI 0: proj -> out0b=x_ssm bf16 (col<1024), out1b=silu(gate) bf16 (col>=1024)
// EPI 1: dt/BC -> out0b=softplus(v+b_dt) bf16 (col<1024), out1=BC raw fp32 (stride 32)
// EPI 2: out0 = v + bias0 + addx  (residual pre-LN, fp32)
template<int EPI, int BM, int BN, int NT>
__global__ __launch_bounds__(NT)
void gemm_bt(const __bf16* __restrict__ A, const __bf16* __restrict__ Bt,
             int N, int K,
             const float* __restrict__ bias0, const float* __restrict__ bias1,
             float* __restrict__ out0, float* __restrict__ out1,
             const float* __restrict__ addx,
             __bf16* __restrict__ out0b, __bf16* __restrict__ out1b)
{
  constexpr int NWAVE = NT/64;
  constexpr int WC_N  = NWAVE/2;     // waves along N
  constexpr int WM    = BM/2;        // wave tile rows
  constexpr int WN    = BN/WC_N;     // wave tile cols
  constexpr int MR    = WM/16, NR = WN/16;

  __shared__ __align__(16) __bf16 As[2][BM*BK];
  __shared__ __align__(16) __bf16 Bs[2][BN*BK];
  const int tid = threadIdx.x, wave = tid>>6, lane = tid&63;

  // bijective XCD-chunk swizzle: all grids here have nwg % 8 == 0
  const int orig = blockIdx.y * gridDim.x + blockIdx.x;
  const int nwg  = gridDim.x * gridDim.y;
  const int cpx  = nwg >> 3;
  const int swz  = (orig & 7) * cpx + (orig >> 3);
  const int m0 = (swz / gridDim.x) * BM;
  const int n0 = (swz % gridDim.x) * BN;
  const int wr = wave / WC_N, wc = wave % WC_N;

  f32x4 acc[MR][NR];
  #pragma unroll
  for (int a=0;a<MR;a++)
    #pragma unroll
    for (int b=0;b<NR;b++) acc[a][b] = (f32x4){0.f,0.f,0.f,0.f};

  // staging: BM*BK/8 16B-chunks per matrix; 2 per thread. LDS dest is
  // wave-uniform base + lane*16 (c0=tid, c1=tid+NT) as global_load_lds requires.
  const int c0 = tid, c1 = tid + NT;
  const int r0 = c0>>2, s0 = (c0&3)*8;
  const int r1 = c1>>2, s1 = (c1&3)*8;
  const int arow = wr*WM + (lane&15), brow = wc*WN + (lane&15);
  const int kg = (lane>>4)*8;

  // prologue: stage K-tile 0 into buf 0
  gload16(&A [(size_t)(m0+r0)*K + s0], &As[0][c0*8]);
  gload16(&A [(size_t)(m0+r1)*K + s1], &As[0][c1*8]);
  gload16(&Bt[(size_t)(n0+r0)*K + s0], &Bs[0][c0*8]);
  gload16(&Bt[(size_t)(n0+r1)*K + s1], &Bs[0][c1*8]);
  __syncthreads();

  const int nIter = K/BK;
  int buf = 0;
  for (int it=0; it<nIter; ++it){
    // issue next-tile stage FIRST (overlaps with ds_read+MFMA below)
    if (it+1 < nIter){
      const int kn = (it+1)*BK;
      gload16(&A [(size_t)(m0+r0)*K + kn + s0], &As[buf^1][c0*8]);
      gload16(&A [(size_t)(m0+r1)*K + kn + s1], &As[buf^1][c1*8]);
      gload16(&Bt[(size_t)(n0+r0)*K + kn + s0], &Bs[buf^1][c0*8]);
      gload16(&Bt[(size_t)(n0+r1)*K + kn + s1], &Bs[buf^1][c1*8]);
    }
    bf16x8 af[MR], bfv[NR];
    #pragma unroll
    for (int m=0;m<MR;m++) af[m]  = *(const bf16x8*)&As[buf][(arow+m*16)*BK + kg];
    #pragma unroll
    for (int n=0;n<NR;n++) bfv[n] = *(const bf16x8*)&Bs[buf][(brow+n*16)*BK + kg];
    #pragma unroll
    for (int m=0;m<MR;m++)
      #pragma unroll
      for (int n=0;n<NR;n++)
        acc[m][n] = __builtin_amdgcn_mfma_f32_16x16x32_bf16(af[m], bfv[n], acc[m][n], 0,0,0);
    // one barrier per K-step: drains next-tile loads + all reads of buf done
    __syncthreads();
    buf ^= 1;
  }

  const int cr = (lane>>4)*4, cc = lane&15;
  #pragma unroll
  for (int m=0;m<MR;m++){
    const int row = m0 + wr*WM + m*16 + cr;
    #pragma unroll
    for (int n=0;n<NR;n++){
      const int col = n0 + wc*WN + n*16 + cc;
      if (col >= N) continue;
      #pragma unroll
      for (int r=0;r<4;r++){
        float v = acc[m][n][r];
        const size_t ri = (size_t)(row + r);
        if constexpr (EPI==0){
          v += bias0[col];
          if (col < D_MODEL) out0b[ri*D_MODEL + col] = (__bf16)v;
          else               out1b[ri*D_MODEL + (col-D_MODEL)] = (__bf16)(v * sigmoidf_(v));
        } else if constexpr (EPI==1){
          if (col < D_MODEL){
            v += bias0[col];
            const float sp = (v > 20.f) ? v : __logf(1.f + __expf(v));
            out0b[ri*D_MODEL + col] = (__bf16)sp;
          } else {
            v += bias1[col-D_MODEL];
            out1[ri*32 + (col-D_MODEL)] = v;
          }
        } else {
          v += bias0[col] + addx[ri*D_MODEL + col];
          out0[ri*D_MODEL + col] = v;
        }
      }
    }
  }
}

// ---------------- causal depthwise conv(4) + silu (bf16 in, bf16 out) ----------------
__global__ __launch_bounds__(256) void conv_silu_kernel(
    const __bf16* __restrict__ xssm, const float* __restrict__ cw, const float* __restrict__ cb,
    __bf16* __restrict__ xcb)
{
  const int bt = blockIdx.x;            // b*T + t
  const int t  = bt & (T_SEQ-1);
  const int d  = threadIdx.x*4;
  float4 w[4];
  #pragma unroll
  for (int j=0;j<4;j++) w[j] = *(const float4*)&cw[(d+j)*4];
  float4 acc = *(const float4*)&cb[d];
  #pragma unroll
  for (int k=0;k<4;k++){
    const int tt = t-3+k;
    if (tt >= 0){
      bf16x4 xv = ((const bf16x4*)xssm)[((size_t)(bt-3+k)*D_MODEL + d)>>2];
      acc.x = fmaf((float)xv[0], ((const float*)&w[0])[k], acc.x);
      acc.y = fmaf((float)xv[1], ((const float*)&w[1])[k], acc.y);
      acc.z = fmaf((float)xv[2], ((const float*)&w[2])[k], acc.z);
      acc.w = fmaf((float)xv[3], ((const float*)&w[3])[k], acc.w);
    }
  }
  acc.x *= sigmoidf_(acc.x); acc.y *= sigmoidf_(acc.y);
  acc.z *= sigmoidf_(acc.z); acc.w *= sigmoidf_(acc.w);
  bf16x4 o; o[0]=(__bf16)acc.x; o[1]=(__bf16)acc.y; o[2]=(__bf16)acc.z; o[3]=(__bf16)acc.w;
  ((bf16x4*)xcb)[((size_t)bt*D_MODEL + d)>>2] = o;
}

// ---------------- segmented selective scan, lane-owns-d ----------------
// Phase 1: per segment (h0=0): E = local end state (16/lane), P = exp(a * sum_dt)
__global__ __launch_bounds__(128) void scan_p1(
    const __bf16* __restrict__ xcb, const __bf16* __restrict__ dtb, const float* __restrict__ BCb,
    const float* __restrict__ A_log, float* __restrict__ Ebuf, float* __restrict__ Pbuf)
{
  const int tid = threadIdx.x;
  const int d = blockIdx.x*128 + tid;
  const int b = blockIdx.y, sg = blockIdx.z;
  float an[16];
  {
    f32x4 a0 = *(const f32x4*)&A_log[(size_t)d*16];
    f32x4 a1 = *(const f32x4*)&A_log[(size_t)d*16+4];
    f32x4 a2 = *(const f32x4*)&A_log[(size_t)d*16+8];
    f32x4 a3 = *(const f32x4*)&A_log[(size_t)d*16+12];
    #pragma unroll
    for (int n=0;n<4;n++){ an[n]=-__expf(a0[n]); an[4+n]=-__expf(a1[n]);
                           an[8+n]=-__expf(a2[n]); an[12+n]=-__expf(a3[n]); }
  }
  __shared__ float sB[2][CHUNK][16];
  const size_t base = (size_t)b*T_SEQ + (size_t)sg*SEGLEN;
  const int sr = tid>>4, sc = tid&15;   // stage coords (128 threads = 8x16)

  float dtr[CHUNK], xcr[CHUNK];
  sB[0][sr][sc] = BCb[(base + sr)*32 + sc];
  #pragma unroll
  for (int t=0;t<CHUNK;t++){
    dtr[t] = (float)dtb[(base+t)*D_MODEL + d];
    xcr[t] = (float)xcb[(base+t)*D_MODEL + d];
  }
  __syncthreads();

  float h[16];
  #pragma unroll
  for (int n=0;n<16;n++) h[n]=0.f;
  float sdt = 0.f;

  for (int c=0;c<NCHUNK;c++){
    float dtn[CHUNK], xcn[CHUNK], bnv = 0.f;
    if (c+1 < NCHUNK){
      const size_t nb = base + (size_t)(c+1)*CHUNK;
      #pragma unroll
      for (int t=0;t<CHUNK;t++){
        dtn[t] = (float)dtb[(nb+t)*D_MODEL + d];
        xcn[t] = (float)xcb[(nb+t)*D_MODEL + d];
      }
      bnv = BCb[(nb + sr)*32 + sc];
    }
    const int cb = c&1;
    #pragma unroll
    for (int t=0;t<CHUNK;t++){
      const float dtv = dtr[t], u = dtv*xcr[t];
      sdt += dtv;
      #pragma unroll
      for (int n=0;n<16;n++){
        const float dA = __expf(dtv*an[n]);
        h[n] = fmaf(h[n], dA, u*sB[cb][t][n]);
      }
    }
    if (c+1 < NCHUNK){
      sB[cb^1][sr][sc] = bnv;
      #pragma unroll
      for (int t=0;t<CHUNK;t++){ dtr[t]=dtn[t]; xcr[t]=xcn[t]; }
    }
    __syncthreads();
  }
  const size_t o = ((((size_t)sg*N_BATCH)+b)*D_MODEL + d)*16;
  #pragma unroll
  for (int n=0;n<16;n++){
    Ebuf[o+n] = h[n];
    Pbuf[o+n] = __expf(an[n]*sdt);
  }
}

// Phase 2: carry scan across segments; Ebuf[idx] becomes the carry-IN for segment s
__global__ __launch_bounds__(256) void scan_p2(float* __restrict__ Ebuf,
                                               const float* __restrict__ Pbuf)
{
  const size_t g = (size_t)blockIdx.x*256 + threadIdx.x;  // (b,d,n)
  float c = 0.f;
  #pragma unroll
  for (int s=0;s<SEGS;s++){
    const size_t idx = (size_t)s*(N_BATCH*D_MODEL*N_STATE) + g;
    const float e = Ebuf[idx];
    const float p = Pbuf[idx];
    Ebuf[idx] = c;
    c = fmaf(p, c, e);
  }
}

// Phase 3: scan within segment from carry; y = (C·h + D·xc)*gate -> bf16
__global__ __launch_bounds__(128) void scan_p3(
    const __bf16* __restrict__ xcb, const __bf16* __restrict__ dtb, const float* __restrict__ BCb,
    const float* __restrict__ A_log, const float* __restrict__ Dvec,
    const __bf16* __restrict__ gsil, const float* __restrict__ Ebuf,
    __bf16* __restrict__ ybf)
{
  const int tid = threadIdx.x;
  const int d = blockIdx.x*128 + tid;
  const int b = blockIdx.y, sg = blockIdx.z;
  float an[16];
  {
    f32x4 a0 = *(const f32x4*)&A_log[(size_t)d*16];
    f32x4 a1 = *(const f32x4*)&A_log[(size_t)d*16+4];
    f32x4 a2 = *(const f32x4*)&A_log[(size_t)d*16+8];
    f32x4 a3 = *(const f32x4*)&A_log[(size_t)d*16+12];
    #pragma unroll
    for (int n=0;n<4;n++){ an[n]=-__expf(a0[n]); an[4+n]=-__expf(a1[n]);
                           an[8+n]=-__expf(a2[n]); an[12+n]=-__expf(a3[n]); }
  }
  const float Dd = Dvec[d];
  __shared__ float sBC[2][CHUNK][32];
  const size_t base = (size_t)b*T_SEQ + (size_t)sg*SEGLEN;
  const int sr = tid>>4, sc = tid&15;

  float h[16];
  {
    const size_t o = ((((size_t)sg*N_BATCH)+b)*D_MODEL + d)*16;
    f32x4 e0 = *(const f32x4*)&Ebuf[o];
    f32x4 e1 = *(const f32x4*)&Ebuf[o+4];
    f32x4 e2 = *(const f32x4*)&Ebuf[o+8];
    f32x4 e3 = *(const f32x4*)&Ebuf[o+12];
    #pragma unroll
    for (int n=0;n<4;n++){ h[n]=e0[n]; h[4+n]=e1[n]; h[8+n]=e2[n]; h[12+n]=e3[n]; }
  }

  float dtr[CHUNK], xcr[CHUNK], gsr[CHUNK];
  sBC[0][sr][sc]    = BCb[(base + sr)*32 + sc];
  sBC[0][sr][16+sc] = BCb[(base + sr)*32 + 16 + sc];
  #pragma unroll
  for (int t=0;t<CHUNK;t++){
    dtr[t] = (float)dtb[(base+t)*D_MODEL + d];
    xcr[t] = (float)xcb[(base+t)*D_MODEL + d];
    gsr[t] = (float)gsil[(base+t)*D_MODEL + d];
  }
  __syncthreads();

  for (int c=0;c<NCHUNK;c++){
    float dtn[CHUNK], xcn[CHUNK], gsn[CHUNK], bnv=0.f, cnv=0.f;
    if (c+1 < NCHUNK){
      const size_t nb = base + (size_t)(c+1)*CHUNK;
      #pragma unroll
      for (int t=0;t<CHUNK;t++){
        dtn[t] = (float)dtb[(nb+t)*D_MODEL + d];
        xcn[t] = (float)xcb[(nb+t)*D_MODEL + d];
        gsn[t] = (float)gsil[(nb+t)*D_MODEL + d];
      }
      bnv = BCb[(nb + sr)*32 + sc];
      cnv = BCb[(nb + sr)*32 + 16 + sc];
    }
    const int cb = c&1;
    #pragma unroll
    for (int t=0;t<CHUNK;t++){
      const float dtv = dtr[t], xcv = xcr[t], u = dtv*xcv;
      #pragma unroll
      for (int n=0;n<16;n++){
        const float dA = __expf(dtv*an[n]);
        h[n] = fmaf(h[n], dA, u*sBC[cb][t][n]);
      }
      float yv = Dd*xcv;
      #pragma unroll
      for (int n=0;n<16;n++) yv = fmaf(h[n], sBC[cb][t][16+n], yv);
      ybf[(base + (size_t)c*CHUNK + t)*D_MODEL + d] = (__bf16)(yv * gsr[t]);
    }
    if (c+1 < NCHUNK){
      sBC[cb^1][sr][sc]    = bnv;
      sBC[cb^1][sr][16+sc] = cnv;
      #pragma unroll
      for (int t=0;t<CHUNK;t++){ dtr[t]=dtn[t]; xcr[t]=xcn[t]; gsr[t]=gsn[t]; }
    }
    __syncthreads();
  }
}

// ---------------- layernorm, in place on d_out ----------------
__global__ __launch_bounds__(256) void ln_kernel(float* __restrict__ io,
    const float* __restrict__ g, const float* __restrict__ b)
{
  const int row = blockIdx.x, tid = threadIdx.x;
  float4* p = (float4*)(io + (size_t)row*D_MODEL);
  float4 v = p[tid];
  float s  = v.x+v.y+v.z+v.w;
  float s2 = v.x*v.x + v.y*v.y + v.z*v.z + v.w*v.w;
  #pragma unroll
  for (int o=1;o<64;o<<=1){ s += __shfl_xor(s,o); s2 += __shfl_xor(s2,o); }
  __shared__ float red[8];
  const int wave = tid>>6, lane = tid&63;
  if (lane==0){ red[wave]=s; red[4+wave]=s2; }
  __syncthreads();
  s  = red[0]+red[1]+red[2]+red[3];
  s2 = red[4]+red[5]+red[6]+red[7];
  const float mu  = s*(1.f/D_MODEL);
  const float var = s2*(1.f/D_MODEL) - mu*mu;
  const float rs  = rsqrtf(var + 1e-5f);
  float4 gg = ((const float4*)g)[tid], bb = ((const float4*)b)[tid];
  float4 o;
  o.x = (v.x-mu)*rs*gg.x + bb.x;
  o.y = (v.y-mu)*rs*gg.y + bb.y;
  o.z = (v.z-mu)*rs*gg.z + bb.z;
  o.w = (v.w-mu)*rs*gg.w + bb.w;
  p[tid] = o;
}

extern "C" void kernel_launch(void* const* d_in, const int* in_sizes, int n_in,
                              void* d_out, int out_size, void* d_ws, size_t ws_size,
                              hipStream_t stream)
{
  (void)in_sizes; (void)n_in; (void)out_size; (void)ws_size;
  const float* x      = (const float*)d_in[0];
  const float* W_in   = (const float*)d_in[1];
  const float* b_in   = (const float*)d_in[2];
  const float* conv_w = (const float*)d_in[3];
  const float* conv_b = (const float*)d_in[4];
  const float* W_bc   = (const float*)d_in[5];
  const float* b_bc   = (const float*)d_in[6];
  const float* W_dt   = (const float*)d_in[7];
  const float* b_dt   = (const float*)d_in[8];
  const float* A_log  = (const float*)d_in[9];
  const float* Dv     = (const float*)d_in[10];
  const float* W_out  = (const float*)d_in[11];
  const float* b_out  = (const float*)d_in[12];
  const float* ln_g   = (const float*)d_in[13];
  const float* ln_b   = (const float*)d_in[14];

  char* Wp = (char*)d_ws;
  __bf16* x_bf    = (__bf16*)(Wp + 0);          // 16 MB
  __bf16* WinT    = (__bf16*)(Wp + 16777216);   //  4 MB   [2048][1024]
  __bf16* WdbT    = (__bf16*)(Wp + 20971520);   // 2.5 MB  [1280][1024] (dt 0..1023, bc 1024..1055, zero pad to 1280)
  __bf16* WoutT   = (__bf16*)(Wp + 23592960);   //  2 MB   [1024][1024]
  __bf16* xssm_bf = (__bf16*)(Wp + 25690112);   // 16 MB
  float*  Ebuf    = (float*) (Wp + 42467328);   //  8 MB
  float*  Pbuf    = (float*) (Wp + 50855936);   //  8 MB
  __bf16* gsil_bf = (__bf16*)(Wp + 59244544);   // 16 MB
  __bf16* xcb     = (__bf16*)(Wp + 76021760);   // 16 MB
  __bf16* dtb     = (__bf16*)(Wp + 92798976);   // 16 MB
  float*  BCb     = (float*) (Wp + 109576192);  //  1 MB
  __bf16* ybf     = (__bf16*)(Wp + 110624768);  // 16 MB   -> total ~127.4 MB

  // zero padded rows of WdbT (rows 1056..1279 feed discarded tile cols)
  hipMemsetAsync(WdbT, 0, (size_t)1280*1024*2, stream);

  cast_bf16_kernel<<<8192,256,0,stream>>>(x, x_bf, (M_ROWS*D_MODEL)/4);
  transpose_cast_kernel<<<dim3(64,32), dim3(32,8),0,stream>>>(W_in,  WinT,  1024, 2048);
  transpose_cast_kernel<<<dim3(32,32), dim3(32,8),0,stream>>>(W_dt,  WdbT,  1024, 1024);
  transpose_cast_kernel<<<dim3(1,32),  dim3(32,8),0,stream>>>(W_bc,  WdbT + (size_t)1024*1024, 1024, 32);
  transpose_cast_kernel<<<dim3(32,32), dim3(32,8),0,stream>>>(W_out, WoutT, 1024, 1024);

  // proj = x @ W_in + b_in ; -> bf16 x_ssm, bf16 silu(gate)   [256² tile]
  gemm_bt<0,256,256,512><<<dim3(8,32),512,0,stream>>>(x_bf, WinT, 2048, 1024, b_in, nullptr,
                                           nullptr, nullptr, nullptr, xssm_bf, gsil_bf);
  conv_silu_kernel<<<M_ROWS,256,0,stream>>>(xssm_bf, conv_w, conv_b, xcb);
  // [dt|BC] ; N=1056 real cols, grid covers 1280 (pad discarded)   [256² tile]
  gemm_bt<1,256,256,512><<<dim3(5,32),512,0,stream>>>(xcb, WdbT, 1056, 1024, b_dt, b_bc,
                                          nullptr, BCb, nullptr, dtb, nullptr);

  scan_p1<<<dim3(8,4,SEGS),128,0,stream>>>(xcb, dtb, BCb, A_log, Ebuf, Pbuf);
  scan_p2<<<256,256,0,stream>>>(Ebuf, Pbuf);
  scan_p3<<<dim3(8,4,SEGS),128,0,stream>>>(xcb, dtb, BCb, A_log, Dv, gsil_bf, Ebuf, ybf);

  // out = y @ W_out + b_out + x   [128² tile: N=1024 -> only 128 big blocks, keep small]
  gemm_bt<2,128,128,256><<<dim3(8,64),256,0,stream>>>(ybf, WoutT, 1024, 1024, b_out, nullptr,
                                          (float*)d_out, nullptr, x, nullptr, nullptr);
  ln_kernel<<<M_ROWS,256,0,stream>>>((float*)d_out, ln_g, ln_b);
}

// Round 11
// 389.882 us; speedup vs baseline: 1.0774x; 1.0774x over previous
//
#include <hip/hip_runtime.h>
#include <stdint.h>

#define D_MODEL 1024
#define T_SEQ   2048
#define N_BATCH 4
#define M_ROWS  (N_BATCH*T_SEQ)   // 8192
#define N_STATE 16
#define SEGS    64
#define SEGLEN  (T_SEQ/SEGS)      // 32
#define CHUNK   8
#define NCHUNK  (SEGLEN/CHUNK)    // 4

typedef float  f32x4  __attribute__((ext_vector_type(4)));
typedef __bf16 bf16x8 __attribute__((ext_vector_type(8)));
typedef __bf16 bf16x4 __attribute__((ext_vector_type(4)));

__device__ __forceinline__ void gload16(const void* g, void* l) {
  __builtin_amdgcn_global_load_lds(
      (const __attribute__((address_space(1))) uint32_t*)g,
      (__attribute__((address_space(3))) uint32_t*)l, 16, 0, 0);
}

__device__ __forceinline__ float sigmoidf_(float v){ return 1.f/(1.f+__expf(-v)); }

// ---------------- merged prep: cast x, transpose+cast 4 weights, zero WdbT pad ----------------
// sections: [0,8192) cast x | [8192,10240) W_in | [10240,11264) W_dt
//           [11264,11296) W_bc | [11296,12320) W_out | [12320,12368) zero pad
__global__ __launch_bounds__(256) void prep_kernel(
    const float* __restrict__ x, __bf16* __restrict__ x_bf,
    const float* __restrict__ W_in, __bf16* __restrict__ WinT,
    const float* __restrict__ W_dt, const float* __restrict__ W_bc, __bf16* __restrict__ WdbT,
    const float* __restrict__ W_out, __bf16* __restrict__ WoutT)
{
  __shared__ float tile[32][33];
  const int bid = blockIdx.x, tid = threadIdx.x;

  if (bid < 8192){                       // cast x -> bf16 (float4 per thread)
    const int i = bid*256 + tid;         // 2,097,152 float4s exactly
    float4 v = ((const float4*)x)[i];
    bf16x4 o; o[0]=(__bf16)v.x; o[1]=(__bf16)v.y; o[2]=(__bf16)v.z; o[3]=(__bf16)v.w;
    ((bf16x4*)x_bf)[i] = o;
    return;
  }
  int b2 = bid - 8192;
  const float* W; __bf16* out; int K, N, xt, yt;
  if (b2 < 2048){ W=W_in; out=WinT; K=1024; N=2048; xt=b2&63; yt=b2>>6; }
  else if ((b2 -= 2048) < 1024){ W=W_dt; out=WdbT; K=1024; N=1024; xt=b2&31; yt=b2>>5; }
  else if ((b2 -= 1024) < 32){ W=W_bc; out=WdbT+(size_t)1024*1024; K=1024; N=32; xt=0; yt=b2; }
  else if ((b2 -= 32) < 1024){ W=W_out; out=WoutT; K=1024; N=1024; xt=b2&31; yt=b2>>5; }
  else {                                 // zero rows 1056..1151 of WdbT
    b2 -= 1024;
    bf16x8 z;
    #pragma unroll
    for (int i=0;i<8;i++) z[i] = (__bf16)0.f;
    *(bf16x8*)&WdbT[(size_t)1056*1024 + (size_t)b2*2048 + tid*8] = z;
    return;
  }
  const int tx = tid&31, ty = tid>>5;
  const int n0 = xt*32, k0 = yt*32;
  #pragma unroll
  for (int i=0;i<4;i++)
    tile[ty+i*8][tx] = W[(size_t)(k0+ty+i*8)*N + n0+tx];
  __syncthreads();
  #pragma unroll
  for (int i=0;i<4;i++)
    out[(size_t)(n0+ty+i*8)*K + k0+tx] = (__bf16)tile[tx][ty+i*8];
}

// ---- MFMA GEMM: C = A(MxK)*Bt(NxK)^T ----
// R8-proven config: 128x128 tile, 256 thr (4 waves 2x2), 2-phase dbuf,
// ONE __syncthreads per K-step, XCD-chunk swizzle. 32KB LDS -> 4 blocks/CU.
#define BK 32

// EPI 0: proj -> out0b=x_ssm bf16 (col<1024), out1b=silu(gate) bf16 (col>=1024)
// EPI 1: dt/BC -> out0b=softplus(v+b_dt) bf16 (col<1024), out1=BC raw fp32 (stride 32)
// EPI 2: out0 = v + bias0 + addx  (residual pre-LN, fp32)
template<int EPI, int BM, int BN, int NT>
__global__ __launch_bounds__(NT)
void gemm_bt(const __bf16* __restrict__ A, const __bf16* __restrict__ Bt,
             int N, int K,
             const float* __restrict__ bias0, const float* __restrict__ bias1,
             float* __restrict__ out0, float* __restrict__ out1,
             const float* __restrict__ addx,
             __bf16* __restrict__ out0b, __bf16* __restrict__ out1b)
{
  constexpr int NWAVE = NT/64;
  constexpr int WC_N  = NWAVE/2;
  constexpr int WM    = BM/2;
  constexpr int WN    = BN/WC_N;
  constexpr int MR    = WM/16, NR = WN/16;

  __shared__ __align__(16) __bf16 As[2][BM*BK];
  __shared__ __align__(16) __bf16 Bs[2][BN*BK];
  const int tid = threadIdx.x, wave = tid>>6, lane = tid&63;

  // bijective XCD-chunk swizzle: all grids here have nwg % 8 == 0
  const int orig = blockIdx.y * gridDim.x + blockIdx.x;
  const int nwg  = gridDim.x * gridDim.y;
  const int cpx  = nwg >> 3;
  const int swz  = (orig & 7) * cpx + (orig >> 3);
  const int m0 = (swz / gridDim.x) * BM;
  const int n0 = (swz % gridDim.x) * BN;
  const int wr = wave / WC_N, wc = wave % WC_N;

  f32x4 acc[MR][NR];
  #pragma unroll
  for (int a=0;a<MR;a++)
    #pragma unroll
    for (int b=0;b<NR;b++) acc[a][b] = (f32x4){0.f,0.f,0.f,0.f};

  const int c0 = tid, c1 = tid + NT;
  const int r0 = c0>>2, s0 = (c0&3)*8;
  const int r1 = c1>>2, s1 = (c1&3)*8;
  const int arow = wr*WM + (lane&15), brow = wc*WN + (lane&15);
  const int kg = (lane>>4)*8;

  // prologue: stage K-tile 0 into buf 0
  gload16(&A [(size_t)(m0+r0)*K + s0], &As[0][c0*8]);
  gload16(&A [(size_t)(m0+r1)*K + s1], &As[0][c1*8]);
  gload16(&Bt[(size_t)(n0+r0)*K + s0], &Bs[0][c0*8]);
  gload16(&Bt[(size_t)(n0+r1)*K + s1], &Bs[0][c1*8]);
  __syncthreads();

  const int nIter = K/BK;
  int buf = 0;
  for (int it=0; it<nIter; ++it){
    if (it+1 < nIter){
      const int kn = (it+1)*BK;
      gload16(&A [(size_t)(m0+r0)*K + kn + s0], &As[buf^1][c0*8]);
      gload16(&A [(size_t)(m0+r1)*K + kn + s1], &As[buf^1][c1*8]);
      gload16(&Bt[(size_t)(n0+r0)*K + kn + s0], &Bs[buf^1][c0*8]);
      gload16(&Bt[(size_t)(n0+r1)*K + kn + s1], &Bs[buf^1][c1*8]);
    }
    bf16x8 af[MR], bfv[NR];
    #pragma unroll
    for (int m=0;m<MR;m++) af[m]  = *(const bf16x8*)&As[buf][(arow+m*16)*BK + kg];
    #pragma unroll
    for (int n=0;n<NR;n++) bfv[n] = *(const bf16x8*)&Bs[buf][(brow+n*16)*BK + kg];
    #pragma unroll
    for (int m=0;m<MR;m++)
      #pragma unroll
      for (int n=0;n<NR;n++)
        acc[m][n] = __builtin_amdgcn_mfma_f32_16x16x32_bf16(af[m], bfv[n], acc[m][n], 0,0,0);
    __syncthreads();
    buf ^= 1;
  }

  const int cr = (lane>>4)*4, cc = lane&15;
  #pragma unroll
  for (int m=0;m<MR;m++){
    const int row = m0 + wr*WM + m*16 + cr;
    #pragma unroll
    for (int n=0;n<NR;n++){
      const int col = n0 + wc*WN + n*16 + cc;
      if (col >= N) continue;
      #pragma unroll
      for (int r=0;r<4;r++){
        float v = acc[m][n][r];
        const size_t ri = (size_t)(row + r);
        if constexpr (EPI==0){
          v += bias0[col];
          if (col < D_MODEL) out0b[ri*D_MODEL + col] = (__bf16)v;
          else               out1b[ri*D_MODEL + (col-D_MODEL)] = (__bf16)(v * sigmoidf_(v));
        } else if constexpr (EPI==1){
          if (col < D_MODEL){
            v += bias0[col];
            const float sp = (v > 20.f) ? v : __logf(1.f + __expf(v));
            out0b[ri*D_MODEL + col] = (__bf16)sp;
          } else {
            v += bias1[col-D_MODEL];
            out1[ri*32 + (col-D_MODEL)] = v;
          }
        } else {
          v += bias0[col] + addx[ri*D_MODEL + col];
          out0[ri*D_MODEL + col] = v;
        }
      }
    }
  }
}

// ---------------- causal depthwise conv(4) + silu (bf16 in, bf16 out) ----------------
__global__ __launch_bounds__(256) void conv_silu_kernel(
    const __bf16* __restrict__ xssm, const float* __restrict__ cw, const float* __restrict__ cb,
    __bf16* __restrict__ xcb)
{
  const int bt = blockIdx.x;            // b*T + t
  const int t  = bt & (T_SEQ-1);
  const int d  = threadIdx.x*4;
  float4 w[4];
  #pragma unroll
  for (int j=0;j<4;j++) w[j] = *(const float4*)&cw[(d+j)*4];
  float4 acc = *(const float4*)&cb[d];
  #pragma unroll
  for (int k=0;k<4;k++){
    const int tt = t-3+k;
    if (tt >= 0){
      bf16x4 xv = ((const bf16x4*)xssm)[((size_t)(bt-3+k)*D_MODEL + d)>>2];
      acc.x = fmaf((float)xv[0], ((const float*)&w[0])[k], acc.x);
      acc.y = fmaf((float)xv[1], ((const float*)&w[1])[k], acc.y);
      acc.z = fmaf((float)xv[2], ((const float*)&w[2])[k], acc.z);
      acc.w = fmaf((float)xv[3], ((const float*)&w[3])[k], acc.w);
    }
  }
  acc.x *= sigmoidf_(acc.x); acc.y *= sigmoidf_(acc.y);
  acc.z *= sigmoidf_(acc.z); acc.w *= sigmoidf_(acc.w);
  bf16x4 o; o[0]=(__bf16)acc.x; o[1]=(__bf16)acc.y; o[2]=(__bf16)acc.z; o[3]=(__bf16)acc.w;
  ((bf16x4*)xcb)[((size_t)bt*D_MODEL + d)>>2] = o;
}

// ---------------- segmented selective scan, lane-owns-d ----------------
// Phase 1: per segment (h0=0): E = local end state (16/lane), P = exp(a * sum_dt)
__global__ __launch_bounds__(128) void scan_p1(
    const __bf16* __restrict__ xcb, const __bf16* __restrict__ dtb, const float* __restrict__ BCb,
    const float* __restrict__ A_log, float* __restrict__ Ebuf, float* __restrict__ Pbuf)
{
  const int tid = threadIdx.x;
  const int d = blockIdx.x*128 + tid;
  const int b = blockIdx.y, sg = blockIdx.z;
  float an[16];
  {
    f32x4 a0 = *(const f32x4*)&A_log[(size_t)d*16];
    f32x4 a1 = *(const f32x4*)&A_log[(size_t)d*16+4];
    f32x4 a2 = *(const f32x4*)&A_log[(size_t)d*16+8];
    f32x4 a3 = *(const f32x4*)&A_log[(size_t)d*16+12];
    #pragma unroll
    for (int n=0;n<4;n++){ an[n]=-__expf(a0[n]); an[4+n]=-__expf(a1[n]);
                           an[8+n]=-__expf(a2[n]); an[12+n]=-__expf(a3[n]); }
  }
  __shared__ float sB[2][CHUNK][16];
  const size_t base = (size_t)b*T_SEQ + (size_t)sg*SEGLEN;
  const int sr = tid>>4, sc = tid&15;

  float dtr[CHUNK], xcr[CHUNK];
  sB[0][sr][sc] = BCb[(base + sr)*32 + sc];
  #pragma unroll
  for (int t=0;t<CHUNK;t++){
    dtr[t] = (float)dtb[(base+t)*D_MODEL + d];
    xcr[t] = (float)xcb[(base+t)*D_MODEL + d];
  }
  __syncthreads();

  float h[16];
  #pragma unroll
  for (int n=0;n<16;n++) h[n]=0.f;
  float sdt = 0.f;

  for (int c=0;c<NCHUNK;c++){
    float dtn[CHUNK], xcn[CHUNK], bnv = 0.f;
    if (c+1 < NCHUNK){
      const size_t nb = base + (size_t)(c+1)*CHUNK;
      #pragma unroll
      for (int t=0;t<CHUNK;t++){
        dtn[t] = (float)dtb[(nb+t)*D_MODEL + d];
        xcn[t] = (float)xcb[(nb+t)*D_MODEL + d];
      }
      bnv = BCb[(nb + sr)*32 + sc];
    }
    const int cb = c&1;
    #pragma unroll
    for (int t=0;t<CHUNK;t++){
      const float dtv = dtr[t], u = dtv*xcr[t];
      sdt += dtv;
      #pragma unroll
      for (int n=0;n<16;n++){
        const float dA = __expf(dtv*an[n]);
        h[n] = fmaf(h[n], dA, u*sB[cb][t][n]);
      }
    }
    if (c+1 < NCHUNK){
      sB[cb^1][sr][sc] = bnv;
      #pragma unroll
      for (int t=0;t<CHUNK;t++){ dtr[t]=dtn[t]; xcr[t]=xcn[t]; }
    }
    __syncthreads();
  }
  const size_t o = ((((size_t)sg*N_BATCH)+b)*D_MODEL + d)*16;
  #pragma unroll
  for (int n=0;n<16;n++){
    Ebuf[o+n] = h[n];
    Pbuf[o+n] = __expf(an[n]*sdt);
  }
}

// Phase 2: carry scan across segments; Ebuf[idx] becomes the carry-IN for segment s
__global__ __launch_bounds__(256) void scan_p2(float* __restrict__ Ebuf,
                                               const float* __restrict__ Pbuf)
{
  const size_t g = (size_t)blockIdx.x*256 + threadIdx.x;  // (b,d,n)
  float c = 0.f;
  #pragma unroll
  for (int s=0;s<SEGS;s++){
    const size_t idx = (size_t)s*(N_BATCH*D_MODEL*N_STATE) + g;
    const float e = Ebuf[idx];
    const float p = Pbuf[idx];
    Ebuf[idx] = c;
    c = fmaf(p, c, e);
  }
}

// Phase 3: scan within segment from carry; y = (C·h + D·xc)*gate -> bf16
__global__ __launch_bounds__(128) void scan_p3(
    const __bf16* __restrict__ xcb, const __bf16* __restrict__ dtb, const float* __restrict__ BCb,
    const float* __restrict__ A_log, const float* __restrict__ Dvec,
    const __bf16* __restrict__ gsil, const float* __restrict__ Ebuf,
    __bf16* __restrict__ ybf)
{
  const int tid = threadIdx.x;
  const int d = blockIdx.x*128 + tid;
  const int b = blockIdx.y, sg = blockIdx.z;
  float an[16];
  {
    f32x4 a0 = *(const f32x4*)&A_log[(size_t)d*16];
    f32x4 a1 = *(const f32x4*)&A_log[(size_t)d*16+4];
    f32x4 a2 = *(const f32x4*)&A_log[(size_t)d*16+8];
    f32x4 a3 = *(const f32x4*)&A_log[(size_t)d*16+12];
    #pragma unroll
    for (int n=0;n<4;n++){ an[n]=-__expf(a0[n]); an[4+n]=-__expf(a1[n]);
                           an[8+n]=-__expf(a2[n]); an[12+n]=-__expf(a3[n]); }
  }
  const float Dd = Dvec[d];
  __shared__ float sBC[2][CHUNK][32];
  const size_t base = (size_t)b*T_SEQ + (size_t)sg*SEGLEN;
  const int sr = tid>>4, sc = tid&15;

  float h[16];
  {
    const size_t o = ((((size_t)sg*N_BATCH)+b)*D_MODEL + d)*16;
    f32x4 e0 = *(const f32x4*)&Ebuf[o];
    f32x4 e1 = *(const f32x4*)&Ebuf[o+4];
    f32x4 e2 = *(const f32x4*)&Ebuf[o+8];
    f32x4 e3 = *(const f32x4*)&Ebuf[o+12];
    #pragma unroll
    for (int n=0;n<4;n++){ h[n]=e0[n]; h[4+n]=e1[n]; h[8+n]=e2[n]; h[12+n]=e3[n]; }
  }

  float dtr[CHUNK], xcr[CHUNK], gsr[CHUNK];
  sBC[0][sr][sc]    = BCb[(base + sr)*32 + sc];
  sBC[0][sr][16+sc] = BCb[(base + sr)*32 + 16 + sc];
  #pragma unroll
  for (int t=0;t<CHUNK;t++){
    dtr[t] = (float)dtb[(base+t)*D_MODEL + d];
    xcr[t] = (float)xcb[(base+t)*D_MODEL + d];
    gsr[t] = (float)gsil[(base+t)*D_MODEL + d];
  }
  __syncthreads();

  for (int c=0;c<NCHUNK;c++){
    float dtn[CHUNK], xcn[CHUNK], gsn[CHUNK], bnv=0.f, cnv=0.f;
    if (c+1 < NCHUNK){
      const size_t nb = base + (size_t)(c+1)*CHUNK;
      #pragma unroll
      for (int t=0;t<CHUNK;t++){
        dtn[t] = (float)dtb[(nb+t)*D_MODEL + d];
        xcn[t] = (float)xcb[(nb+t)*D_MODEL + d];
        gsn[t] = (float)gsil[(nb+t)*D_MODEL + d];
      }
      bnv = BCb[(nb + sr)*32 + sc];
      cnv = BCb[(nb + sr)*32 + 16 + sc];
    }
    const int cb = c&1;
    #pragma unroll
    for (int t=0;t<CHUNK;t++){
      const float dtv = dtr[t], xcv = xcr[t], u = dtv*xcv;
      #pragma unroll
      for (int n=0;n<16;n++){
        const float dA = __expf(dtv*an[n]);
        h[n] = fmaf(h[n], dA, u*sBC[cb][t][n]);
      }
      float yv = Dd*xcv;
      #pragma unroll
      for (int n=0;n<16;n++) yv = fmaf(h[n], sBC[cb][t][16+n], yv);
      ybf[(base + (size_t)c*CHUNK + t)*D_MODEL + d] = (__bf16)(yv * gsr[t]);
    }
    if (c+1 < NCHUNK){
      sBC[cb^1][sr][sc]    = bnv;
      sBC[cb^1][sr][16+sc] = cnv;
      #pragma unroll
      for (int t=0;t<CHUNK;t++){ dtr[t]=dtn[t]; xcr[t]=xcn[t]; gsr[t]=gsn[t]; }
    }
    __syncthreads();
  }
}

// ---------------- layernorm, in place on d_out ----------------
__global__ __launch_bounds__(256) void ln_kernel(float* __restrict__ io,
    const float* __restrict__ g, const float* __restrict__ b)
{
  const int row = blockIdx.x, tid = threadIdx.x;
  float4* p = (float4*)(io + (size_t)row*D_MODEL);
  float4 v = p[tid];
  float s  = v.x+v.y+v.z+v.w;
  float s2 = v.x*v.x + v.y*v.y + v.z*v.z + v.w*v.w;
  #pragma unroll
  for (int o=1;o<64;o<<=1){ s += __shfl_xor(s,o); s2 += __shfl_xor(s2,o); }
  __shared__ float red[8];
  const int wave = tid>>6, lane = tid&63;
  if (lane==0){ red[wave]=s; red[4+wave]=s2; }
  __syncthreads();
  s  = red[0]+red[1]+red[2]+red[3];
  s2 = red[4]+red[5]+red[6]+red[7];
  const float mu  = s*(1.f/D_MODEL);
  const float var = s2*(1.f/D_MODEL) - mu*mu;
  const float rs  = rsqrtf(var + 1e-5f);
  float4 gg = ((const float4*)g)[tid], bb = ((const float4*)b)[tid];
  float4 o;
  o.x = (v.x-mu)*rs*gg.x + bb.x;
  o.y = (v.y-mu)*rs*gg.y + bb.y;
  o.z = (v.z-mu)*rs*gg.z + bb.z;
  o.w = (v.w-mu)*rs*gg.w + bb.w;
  p[tid] = o;
}

extern "C" void kernel_launch(void* const* d_in, const int* in_sizes, int n_in,
                              void* d_out, int out_size, void* d_ws, size_t ws_size,
                              hipStream_t stream)
{
  (void)in_sizes; (void)n_in; (void)out_size; (void)ws_size;
  const float* x      = (const float*)d_in[0];
  const float* W_in   = (const float*)d_in[1];
  const float* b_in   = (const float*)d_in[2];
  const float* conv_w = (const float*)d_in[3];
  const float* conv_b = (const float*)d_in[4];
  const float* W_bc   = (const float*)d_in[5];
  const float* b_bc   = (const float*)d_in[6];
  const float* W_dt   = (const float*)d_in[7];
  const float* b_dt   = (const float*)d_in[8];
  const float* A_log  = (const float*)d_in[9];
  const float* Dv     = (const float*)d_in[10];
  const float* W_out  = (const float*)d_in[11];
  const float* b_out  = (const float*)d_in[12];
  const float* ln_g   = (const float*)d_in[13];
  const float* ln_b   = (const float*)d_in[14];

  char* Wp = (char*)d_ws;
  __bf16* x_bf    = (__bf16*)(Wp + 0);          // 16 MB
  __bf16* WinT    = (__bf16*)(Wp + 16777216);   //  4 MB   [2048][1024]
  __bf16* WdbT    = (__bf16*)(Wp + 20971520);   // 2.25MB  [1152][1024]
  __bf16* WoutT   = (__bf16*)(Wp + 23330816);   //  2 MB   [1024][1024]
  __bf16* xssm_bf = (__bf16*)(Wp + 25427968);   // 16 MB
  __bf16* gsil_bf = (__bf16*)(Wp + 42205184);   // 16 MB
  __bf16* xcb     = (__bf16*)(Wp + 58982400);   // 16 MB
  __bf16* dtb     = (__bf16*)(Wp + 75759616);   // 16 MB
  float*  BCb     = (float*) (Wp + 92536832);   //  1 MB
  __bf16* ybf     = (__bf16*)(Wp + 93585408);   // 16 MB
  float*  Ebuf    = (float*) (Wp + 110362624);  // 16 MB (SEGS=64)
  float*  Pbuf    = (float*) (Wp + 127139840);  // 16 MB  -> total ~144 MB

  // one merged prep launch (replaces cast + 4 transposes + memset)
  prep_kernel<<<12368,256,0,stream>>>(x, x_bf, W_in, WinT, W_dt, W_bc, WdbT, W_out, WoutT);

  // proj = x @ W_in + b_in ; -> bf16 x_ssm, bf16 silu(gate)
  gemm_bt<0,128,128,256><<<dim3(16,64),256,0,stream>>>(x_bf, WinT, 2048, 1024, b_in, nullptr,
                                           nullptr, nullptr, nullptr, xssm_bf, gsil_bf);
  conv_silu_kernel<<<M_ROWS,256,0,stream>>>(xssm_bf, conv_w, conv_b, xcb);
  // [dt|BC] = xc @ [W_dt|W_bc] ; softplus(dt)->bf16, BC->fp32
  gemm_bt<1,128,128,256><<<dim3(9,64),256,0,stream>>>(xcb, WdbT, 1056, 1024, b_dt, b_bc,
                                          nullptr, BCb, nullptr, dtb, nullptr);

  scan_p1<<<dim3(8,4,SEGS),128,0,stream>>>(xcb, dtb, BCb, A_log, Ebuf, Pbuf);
  scan_p2<<<256,256,0,stream>>>(Ebuf, Pbuf);
  scan_p3<<<dim3(8,4,SEGS),128,0,stream>>>(xcb, dtb, BCb, A_log, Dv, gsil_bf, Ebuf, ybf);

  // out = y @ W_out + b_out + x
  gemm_bt<2,128,128,256><<<dim3(8,64),256,0,stream>>>(ybf, WoutT, 1024, 1024, b_out, nullptr,
                                          (float*)d_out, nullptr, x, nullptr, nullptr);
  ln_kernel<<<M_ROWS,256,0,stream>>>((float*)d_out, ln_g, ln_b);
}